// Round 2
// baseline (57.115 us; speedup 1.0000x reference)
//
#include <hip/hip_runtime.h>

// TransE 'rhs' scoring: pred[b,n] = MARGIN - || (s+r)[b] - e[n] ||_2
// B=32, N=200000, D=64, fp32 in/out.
//
// R1 analysis: traffic ideal (50MB fetch) but latency-bound (occ 6.5%,
// hbm 20%, VALU 19%). acc[32][4]=128 VGPR starved the scheduler of
// prefetch registers and only 782 waves existed.
// R2: block=256 (4 waves); wave w handles b in [8w,8w+8), all waves share
// the same n-range so e-loads hit L1/L2 after the first wave. 3128 waves
// (~12/CU), acc[8][4]=32 VGPR -> deep load pipelining via full unroll.

#define C4 16          // D/4 float4 chunks per row
#define NT 4           // n-columns per thread
#define BPW 8          // b-rows per wave
#define MARGIN 9.0f

__global__ __launch_bounds__(256, 4)
void transe_kernel(const float* __restrict__ s_emb,
                   const float* __restrict__ rel_emb,
                   const float* __restrict__ emb_e,
                   float* __restrict__ out,
                   int N) {
    __shared__ float4 q_lds[32 * C4];   // q[b][c] at b*16+c
    __shared__ float  qnorm[32];

    const int t = threadIdx.x;          // 0..255

    // ---- Stage q = s + r into LDS (contiguous), qnorm via 16-lane reduce.
    const float4* s4 = (const float4*)s_emb;
    const float4* r4 = (const float4*)rel_emb;
#pragma unroll
    for (int k = 0; k < 2; ++k) {
        int idx = k * 256 + t;          // 512 float4 = 32 rows x 16 chunks
        float4 sv = s4[idx];
        float4 rv = r4[idx];
        float4 q;
        q.x = sv.x + rv.x; q.y = sv.y + rv.y;
        q.z = sv.z + rv.z; q.w = sv.w + rv.w;
        q_lds[idx] = q;
        float v = q.x*q.x + q.y*q.y + q.z*q.z + q.w*q.w;
        v += __shfl_xor(v, 1, 16);
        v += __shfl_xor(v, 2, 16);
        v += __shfl_xor(v, 4, 16);
        v += __shfl_xor(v, 8, 16);
        if ((t & 15) == 0) qnorm[k * 16 + (t >> 4)] = v;  // b = idx/16
    }
    __syncthreads();

    // ---- Main: wave w covers b0..b0+7; lane owns 4 consecutive n columns.
    const int wave = t >> 6;
    const int lane = t & 63;
    const int b0 = wave * BPW;
    const int tid = blockIdx.x * 64 + lane;
    const long n0 = (long)tid * NT;
    if (n0 >= N) return;                // after syncthreads; N % NT == 0

    const float4* e4 = (const float4*)emb_e;

    float acc[BPW][NT];
#pragma unroll
    for (int bb = 0; bb < BPW; ++bb)
#pragma unroll
        for (int j = 0; j < NT; ++j) acc[bb][j] = 0.f;
    float en[NT] = {0.f, 0.f, 0.f, 0.f};

#pragma unroll
    for (int c = 0; c < C4; ++c) {
        float4 ev[NT];
#pragma unroll
        for (int j = 0; j < NT; ++j) {
            ev[j] = e4[(n0 + j) * C4 + c];
            en[j] = fmaf(ev[j].x, ev[j].x, en[j]);
            en[j] = fmaf(ev[j].y, ev[j].y, en[j]);
            en[j] = fmaf(ev[j].z, ev[j].z, en[j]);
            en[j] = fmaf(ev[j].w, ev[j].w, en[j]);
        }
#pragma unroll
        for (int bb = 0; bb < BPW; ++bb) {
            float4 qv = q_lds[(b0 + bb) * C4 + c];   // wave-uniform broadcast
#pragma unroll
            for (int j = 0; j < NT; ++j) {
                acc[bb][j] = fmaf(qv.x, ev[j].x, acc[bb][j]);
                acc[bb][j] = fmaf(qv.y, ev[j].y, acc[bb][j]);
                acc[bb][j] = fmaf(qv.z, ev[j].z, acc[bb][j]);
                acc[bb][j] = fmaf(qv.w, ev[j].w, acc[bb][j]);
            }
        }
    }

    // ---- Epilogue: d2 = qn + en - 2*dot; pred = MARGIN - sqrt(d2).
    float4* out4 = (float4*)out;
    const long nq = N / 4;
#pragma unroll
    for (int bb = 0; bb < BPW; ++bb) {
        const int b = b0 + bb;
        float qn = qnorm[b];
        float4 o;
        o.x = MARGIN - sqrtf(fmaxf(fmaf(-2.f, acc[bb][0], qn + en[0]), 0.f));
        o.y = MARGIN - sqrtf(fmaxf(fmaf(-2.f, acc[bb][1], qn + en[1]), 0.f));
        o.z = MARGIN - sqrtf(fmaxf(fmaf(-2.f, acc[bb][2], qn + en[2]), 0.f));
        o.w = MARGIN - sqrtf(fmaxf(fmaf(-2.f, acc[bb][3], qn + en[3]), 0.f));
        out4[(long)b * nq + tid] = o;
    }
}

extern "C" void kernel_launch(void* const* d_in, const int* in_sizes, int n_in,
                              void* d_out, int out_size, void* d_ws, size_t ws_size,
                              hipStream_t stream) {
    const float* s = (const float*)d_in[0];
    const float* r = (const float*)d_in[1];
    const float* e = (const float*)d_in[2];
    float* out = (float*)d_out;

    const int N = in_sizes[2] / 64;            // 200000
    const int threads_n = (N + NT - 1) / NT;   // 50000 lanes along n
    const int grid = (threads_n + 63) / 64;    // 782 blocks (256 thr each)

    transe_kernel<<<grid, 256, 0, stream>>>(s, r, e, out, N);
}

// Round 3
// 33.485 us; speedup vs baseline: 1.7057x; 1.7057x over previous
//
#include <hip/hip_runtime.h>

// TransE 'rhs' scoring: pred[b,n] = MARGIN - || (s+r)[b] - e[n] ||_2
// B=32, N=200000, D=64, fp32 in/out.
//
// R2 post-mortem: sharing e across 4 waves of a block doubled HBM fetch
// (50->115 MB) -- temporal drift defeats cache reuse. R3: every thread owns
// one FULL e-row at a time (16 consecutive float4 loads, 16-deep MLP, each
// line read exactly once), waves own disjoint 64-row spans. q panel in LDS,
// inner-loop q reads are wave-uniform broadcasts. acc = one float4 chain per
// b (ILP via 4 components x 32 independent b's). ~90 VGPR -> 4 waves/SIMD.

#define C4 16          // D/4 float4 chunks per row
#define MARGIN 9.0f

__global__ __launch_bounds__(256, 4)
void transe_kernel(const float* __restrict__ s_emb,
                   const float* __restrict__ rel_emb,
                   const float* __restrict__ emb_e,
                   float* __restrict__ out,
                   int N) {
    __shared__ float4 q_lds[32 * C4];   // q[b][c] at b*16+c
    __shared__ float  qnorm[32];

    const int t = threadIdx.x;          // 0..255

    // ---- Stage q = s + r into LDS (contiguous), qnorm via 16-lane reduce.
    const float4* s4 = (const float4*)s_emb;
    const float4* r4 = (const float4*)rel_emb;
#pragma unroll
    for (int k = 0; k < 2; ++k) {
        int idx = k * 256 + t;          // 512 float4 = 32 rows x 16 chunks
        float4 sv = s4[idx];
        float4 rv = r4[idx];
        float4 q;
        q.x = sv.x + rv.x; q.y = sv.y + rv.y;
        q.z = sv.z + rv.z; q.w = sv.w + rv.w;
        q_lds[idx] = q;
        float v = q.x*q.x + q.y*q.y + q.z*q.z + q.w*q.w;
        v += __shfl_xor(v, 1, 16);
        v += __shfl_xor(v, 2, 16);
        v += __shfl_xor(v, 4, 16);
        v += __shfl_xor(v, 8, 16);
        if ((t & 15) == 0) qnorm[k * 16 + (t >> 4)] = v;  // b = idx/16
    }
    __syncthreads();

    // ---- Each thread: one full e-row; wave covers 64 consecutive rows.
    const long row = (long)blockIdx.x * 256 + t;
    if (row >= N) return;               // after the only barrier

    const float4* e4 = (const float4*)emb_e;

    float4 rv[C4];
#pragma unroll
    for (int c = 0; c < C4; ++c) rv[c] = e4[row * C4 + c];   // 16-deep MLP

    float4 en4 = {0.f, 0.f, 0.f, 0.f};
#pragma unroll
    for (int c = 0; c < C4; ++c) {
        en4.x = fmaf(rv[c].x, rv[c].x, en4.x);
        en4.y = fmaf(rv[c].y, rv[c].y, en4.y);
        en4.z = fmaf(rv[c].z, rv[c].z, en4.z);
        en4.w = fmaf(rv[c].w, rv[c].w, en4.w);
    }
    const float en = (en4.x + en4.y) + (en4.z + en4.w);

#pragma unroll
    for (int b = 0; b < 32; ++b) {
        float4 d4 = {0.f, 0.f, 0.f, 0.f};
#pragma unroll
        for (int c = 0; c < C4; ++c) {
            float4 qv = q_lds[b * C4 + c];   // wave-uniform broadcast read
            d4.x = fmaf(qv.x, rv[c].x, d4.x);
            d4.y = fmaf(qv.y, rv[c].y, d4.y);
            d4.z = fmaf(qv.z, rv[c].z, d4.z);
            d4.w = fmaf(qv.w, rv[c].w, d4.w);
        }
        const float dot = (d4.x + d4.y) + (d4.z + d4.w);
        const float d2 = fmaxf(fmaf(-2.f, dot, qnorm[b] + en), 0.f);
        out[(long)b * N + row] = MARGIN - sqrtf(d2);   // 64 consecutive floats/wave
    }
}

extern "C" void kernel_launch(void* const* d_in, const int* in_sizes, int n_in,
                              void* d_out, int out_size, void* d_ws, size_t ws_size,
                              hipStream_t stream) {
    const float* s = (const float*)d_in[0];
    const float* r = (const float*)d_in[1];
    const float* e = (const float*)d_in[2];
    float* out = (float*)d_out;

    const int N = in_sizes[2] / 64;            // 200000
    const int grid = (N + 255) / 256;          // 782 blocks x 256 threads

    transe_kernel<<<grid, 256, 0, stream>>>(s, r, e, out, N);
}